// Round 7
// baseline (263.736 us; speedup 1.0000x reference)
//
#include <hip/hip_runtime.h>

#define D 128
#define NSEG 2048
#define EPSV 1e-6f
#define BLOCK 256
#define QCH 4            // f32x4 chunks per row owned by this block (16 columns)
#define NQ 8             // column splits per segment
#define CPRF 32          // f32x4 chunks per full row
#define RG (BLOCK/QCH)   // 64 row-groups
#define WAVES (BLOCK/64) // 4
#define MAXK 8           // buffered slots/thread: MAXK*RG = 512 rows

typedef float f32x4 __attribute__((ext_vector_type(4)));

// Tiny kernel: segment bounds (lower_bound for 0..NSEG) into d_ws.
__global__ void seg_bounds(const int* __restrict__ seg, int* __restrict__ offs, int N) {
    const int i = blockIdx.x * blockDim.x + threadIdx.x;
    if (i <= NSEG) {
        int lo = 0, hi = N;
        while (lo < hi) {
            int mid = (lo + hi) >> 1;
            if (seg[mid] < i) lo = mid + 1; else hi = mid;
        }
        offs[i] = lo;
    }
}

// 8-way column split: 16384 blocks, buf[8]=32 VGPR -> ~80 total,
// 6 blocks/CU (24 waves) via __launch_bounds__(256,6). Segment slice lives
// in registers between stats and apply -> feat read from HBM exactly once.
__global__ __launch_bounds__(BLOCK, 6) void graphnorm_fused(
    const float* __restrict__ feat,
    const int* __restrict__ offs,
    const float* __restrict__ weight,
    const float* __restrict__ bias,
    const float* __restrict__ mean_scale,
    float* __restrict__ out)
{
    const int bid = blockIdx.x;
    const int s = bid >> 3;        // segment
    const int q = bid & 7;         // column eighth

    const int start = offs[s];     // uniform -> scalar loads, no search chain
    const int end   = offs[s + 1];

    const int t = threadIdx.x;
    const int c = t & (QCH - 1);       // chunk within slice 0..3
    const int g = t >> 2;              // row group 0..63
    const int chunk = q * QCH + c;     // chunk within full row 0..31

    __shared__ f32x4 s_sum[WAVES][QCH];
    __shared__ f32x4 s_sq[WAVES][QCH];

    const f32x4* feat4 = reinterpret_cast<const f32x4*>(feat);
    f32x4* out4 = reinterpret_cast<f32x4*>(out);

    // ---- pass 1a: bulk load into registers (static indices) ----
    f32x4 buf[MAXK];
    #pragma unroll
    for (int k = 0; k < MAXK; ++k) {
        const int r = start + g + k * RG;
        if (r < end) buf[k] = feat4[r * CPRF + chunk];
    }

    // ---- pass 1b: accumulate sum / sumsq from registers ----
    f32x4 s0 = 0.f, q0 = 0.f;
    #pragma unroll
    for (int k = 0; k < MAXK; ++k) {
        const int r = start + g + k * RG;
        if (r < end) {
            s0 += buf[k];
            q0 += buf[k] * buf[k];
        }
    }

    // tail rows beyond the register window (rare, segments > 512 rows)
    const int tail_base = start + g + MAXK * RG;
    for (int r = tail_base; r < end; r += RG) {
        f32x4 v = feat4[r * CPRF + chunk];
        s0 += v;
        q0 += v * v;
    }

    // reduce across the 16 row-groups sharing chunk c within this wave
    #pragma unroll
    for (int i = 0; i < 4; ++i) {
        s0[i] += __shfl_xor(s0[i], 4);
        s0[i] += __shfl_xor(s0[i], 8);
        s0[i] += __shfl_xor(s0[i], 16);
        s0[i] += __shfl_xor(s0[i], 32);
        q0[i] += __shfl_xor(q0[i], 4);
        q0[i] += __shfl_xor(q0[i], 8);
        q0[i] += __shfl_xor(q0[i], 16);
        q0[i] += __shfl_xor(q0[i], 32);
    }

    const int w    = t >> 6;   // wave id 0..3
    const int lane = t & 63;
    if (lane < QCH) {          // lanes 0..3 hold c == lane
        s_sum[w][lane] = s0;
        s_sq[w][lane]  = q0;
    }
    __syncthreads();

    // ---- affine coefficients, computed redundantly by every thread ----
    f32x4 sm = s_sum[0][c];
    f32x4 sg = s_sq[0][c];
    #pragma unroll
    for (int i = 1; i < WAVES; ++i) {
        sm += s_sum[i][c];
        sg += s_sq[i][c];
    }
    const float cnt = (float)max(end - start, 1);
    const float inv = 1.0f / cnt;
    const f32x4 wv  = reinterpret_cast<const f32x4*>(weight)[chunk];
    const f32x4 bi  = reinterpret_cast<const f32x4*>(bias)[chunk];
    const f32x4 msc = reinterpret_cast<const f32x4*>(mean_scale)[chunk];
    f32x4 A, B;
    #pragma unroll
    for (int i = 0; i < 4; ++i) {
        float mean = sm[i] * inv;
        float ms   = mean * msc[i];
        float var  = fmaxf(sg[i] * inv - 2.f * mean * ms + ms * ms, 0.f);
        float istd = rsqrtf(var + EPSV);
        A[i] = wv[i] * istd;
        B[i] = bi[i] - A[i] * ms;
    }

    // ---- pass 2: apply from registers, zero re-loads, nontemporal stores ----
    #pragma unroll
    for (int k = 0; k < MAXK; ++k) {
        const int r = start + g + k * RG;
        if (r < end)
            __builtin_nontemporal_store(A * buf[k] + B, &out4[r * CPRF + chunk]);
    }
    // tail rows: re-read via L2/L3
    for (int r = tail_base; r < end; r += RG) {
        f32x4 v = feat4[r * CPRF + chunk];
        __builtin_nontemporal_store(A * v + B, &out4[r * CPRF + chunk]);
    }
}

extern "C" void kernel_launch(void* const* d_in, const int* in_sizes, int n_in,
                              void* d_out, int out_size, void* d_ws, size_t ws_size,
                              hipStream_t stream) {
    const float* feat       = (const float*)d_in[0];
    const int*   seg        = (const int*)d_in[1];
    const float* weight     = (const float*)d_in[2];
    const float* bias       = (const float*)d_in[3];
    const float* mean_scale = (const float*)d_in[4];
    float* out = (float*)d_out;
    int* offs  = (int*)d_ws;   // (NSEG+1) ints

    const int N = in_sizes[0] / D;   // 1,000,000

    seg_bounds<<<(NSEG + 1 + 255) / 256, 256, 0, stream>>>(seg, offs, N);
    graphnorm_fused<<<NSEG * NQ, BLOCK, 0, stream>>>(
        feat, offs, weight, bias, mean_scale, out);
}

// Round 8
// 203.572 us; speedup vs baseline: 1.2955x; 1.2955x over previous
//
#include <hip/hip_runtime.h>

#define D 128
#define NSEG 2048
#define EPSV 1e-6f
#define BLOCK 512
#define QCH 8            // f32x4 chunks per row owned by this block (32 cols, 128 B)
#define NQ 4             // column splits per segment
#define CPRF 32          // f32x4 chunks per full row
#define RG (BLOCK/QCH)   // 64 row-groups
#define WAVES (BLOCK/64) // 8
#define MAXK 8           // buffered slots/thread: MAXK*RG = 512 rows

typedef float f32x4 __attribute__((ext_vector_type(4)));

// Tiny kernel: segment bounds (lower_bound for 0..NSEG) into d_ws.
__global__ void seg_bounds(const int* __restrict__ seg, int* __restrict__ offs, int N) {
    const int i = blockIdx.x * blockDim.x + threadIdx.x;
    if (i <= NSEG) {
        int lo = 0, hi = N;
        while (lo < hi) {
            int mid = (lo + hi) >> 1;
            if (seg[mid] < i) lo = mid + 1; else hi = mid;
        }
        offs[i] = lo;
    }
}

// 4-way column split (128 B slices — one L2 line each, no cross-XCD sharing).
// BLOCK=512 -> buf[8]=32 VGPR, ~77 total -> 3 blocks/CU, 24 waves/CU.
// Segment slice lives in registers between stats and apply -> feat read once.
__global__ __launch_bounds__(BLOCK, 6) void graphnorm_fused(
    const float* __restrict__ feat,
    const int* __restrict__ offs,
    const float* __restrict__ weight,
    const float* __restrict__ bias,
    const float* __restrict__ mean_scale,
    float* __restrict__ out)
{
    const int bid = blockIdx.x;
    const int s = bid >> 2;        // segment
    const int q = bid & 3;         // column quarter

    const int start = offs[s];     // uniform -> scalar loads
    const int end   = offs[s + 1];

    const int t = threadIdx.x;
    const int c = t & (QCH - 1);       // chunk within slice 0..7
    const int g = t >> 3;              // row group 0..63
    const int chunk = q * QCH + c;     // chunk within full row 0..31

    __shared__ f32x4 s_sum[WAVES][QCH];
    __shared__ f32x4 s_sq[WAVES][QCH];

    const f32x4* feat4 = reinterpret_cast<const f32x4*>(feat);
    f32x4* out4 = reinterpret_cast<f32x4*>(out);

    // ---- pass 1a: bulk load into registers (static indices) ----
    f32x4 buf[MAXK];
    #pragma unroll
    for (int k = 0; k < MAXK; ++k) {
        const int r = start + g + k * RG;
        if (r < end) buf[k] = feat4[r * CPRF + chunk];
    }

    // ---- pass 1b: accumulate sum / sumsq from registers ----
    f32x4 s0 = 0.f, q0 = 0.f;
    #pragma unroll
    for (int k = 0; k < MAXK; ++k) {
        const int r = start + g + k * RG;
        if (r < end) {
            s0 += buf[k];
            q0 += buf[k] * buf[k];
        }
    }

    // tail rows beyond the register window (rare, segments > 512 rows)
    const int tail_base = start + g + MAXK * RG;
    for (int r = tail_base; r < end; r += RG) {
        f32x4 v = feat4[r * CPRF + chunk];
        s0 += v;
        q0 += v * v;
    }

    // reduce across the 8 row-groups sharing chunk c within this wave
    #pragma unroll
    for (int i = 0; i < 4; ++i) {
        s0[i] += __shfl_xor(s0[i], 8);
        s0[i] += __shfl_xor(s0[i], 16);
        s0[i] += __shfl_xor(s0[i], 32);
        q0[i] += __shfl_xor(q0[i], 8);
        q0[i] += __shfl_xor(q0[i], 16);
        q0[i] += __shfl_xor(q0[i], 32);
    }

    const int w    = t >> 6;   // wave id 0..7
    const int lane = t & 63;
    if (lane < QCH) {          // lanes 0..7 hold c == lane
        s_sum[w][lane] = s0;
        s_sq[w][lane]  = q0;
    }
    __syncthreads();

    // ---- affine coefficients, computed redundantly by every thread ----
    f32x4 sm = s_sum[0][c];
    f32x4 sg = s_sq[0][c];
    #pragma unroll
    for (int i = 1; i < WAVES; ++i) {
        sm += s_sum[i][c];
        sg += s_sq[i][c];
    }
    const float cnt = (float)max(end - start, 1);
    const float inv = 1.0f / cnt;
    const f32x4 wv  = reinterpret_cast<const f32x4*>(weight)[chunk];
    const f32x4 bi  = reinterpret_cast<const f32x4*>(bias)[chunk];
    const f32x4 msc = reinterpret_cast<const f32x4*>(mean_scale)[chunk];
    f32x4 A, B;
    #pragma unroll
    for (int i = 0; i < 4; ++i) {
        float mean = sm[i] * inv;
        float ms   = mean * msc[i];
        float var  = fmaxf(sg[i] * inv - 2.f * mean * ms + ms * ms, 0.f);
        float istd = rsqrtf(var + EPSV);
        A[i] = wv[i] * istd;
        B[i] = bi[i] - A[i] * ms;
    }

    // ---- pass 2: apply from registers, zero re-loads, nontemporal stores ----
    #pragma unroll
    for (int k = 0; k < MAXK; ++k) {
        const int r = start + g + k * RG;
        if (r < end)
            __builtin_nontemporal_store(A * buf[k] + B, &out4[r * CPRF + chunk]);
    }
    // tail rows: re-read via L2/L3
    for (int r = tail_base; r < end; r += RG) {
        f32x4 v = feat4[r * CPRF + chunk];
        __builtin_nontemporal_store(A * v + B, &out4[r * CPRF + chunk]);
    }
}

extern "C" void kernel_launch(void* const* d_in, const int* in_sizes, int n_in,
                              void* d_out, int out_size, void* d_ws, size_t ws_size,
                              hipStream_t stream) {
    const float* feat       = (const float*)d_in[0];
    const int*   seg        = (const int*)d_in[1];
    const float* weight     = (const float*)d_in[2];
    const float* bias       = (const float*)d_in[3];
    const float* mean_scale = (const float*)d_in[4];
    float* out = (float*)d_out;
    int* offs  = (int*)d_ws;   // (NSEG+1) ints

    const int N = in_sizes[0] / D;   // 1,000,000

    seg_bounds<<<(NSEG + 1 + 255) / 256, 256, 0, stream>>>(seg, offs, N);
    graphnorm_fused<<<NSEG * NQ, BLOCK, 0, stream>>>(
        feat, offs, weight, bias, mean_scale, out);
}